// Round 9
// baseline (344.499 us; speedup 1.0000x reference)
//
#include <hip/hip_runtime.h>
#include <math.h>

#define N_TOK 16384
#define DIM   768
#define FFD   3072
#define NEXP  8
#define EPSV  1e-6f

typedef __attribute__((ext_vector_type(4))) float f32x4;
typedef __attribute__((ext_vector_type(4))) unsigned short u16x4;
typedef __attribute__((ext_vector_type(8))) unsigned short u16x8;
typedef __attribute__((ext_vector_type(8))) __bf16 bf16x8;

static __device__ __forceinline__ unsigned short f2bf(float f) {
    unsigned int u = __builtin_bit_cast(unsigned int, f);
    u += 0x7fffu + ((u >> 16) & 1u);   // round-to-nearest-even
    return (unsigned short)(u >> 16);
}
static __device__ __forceinline__ bf16x8 as_bf(u16x8 v) {
    return __builtin_bit_cast(bf16x8, v);
}
static __device__ __forceinline__ void gload16(const void* g, void* l) {
    __builtin_amdgcn_global_load_lds(
        (const __attribute__((address_space(1))) unsigned int*)g,
        (__attribute__((address_space(3))) unsigned int*)l, 16, 0, 0);
}

// ---------------------------------------------------------------------------
// Fused setup kernel: blocks [0,4608) convert wi, [4608,9216) convert wo,
// [9216,13312) run RMSNorm+router.
// ---------------------------------------------------------------------------
__global__ __launch_bounds__(256) void k_setup(
    const float* __restrict__ wi, unsigned short* __restrict__ wib,
    const float* __restrict__ wo, unsigned short* __restrict__ wob,
    const float* __restrict__ x, const float* __restrict__ lnw,
    const float* __restrict__ rw,
    float* __restrict__ out_logits, float* __restrict__ out_eidx,
    float* __restrict__ topp, int* __restrict__ eidx,
    unsigned short* __restrict__ xn)
{
    __shared__ float tile[64][68];
    const int t = threadIdx.x;
    const int b = blockIdx.x;

    if (b < 9216) {
        const float* in;
        unsigned short* outp;
        int R, C, bb;
        if (b < 4608) { in = wi; outp = wib; R = DIM; C = FFD; bb = b; }
        else          { in = wo; outp = wob; R = FFD; C = DIM; bb = b - 4608; }
        const int bc = C >> 6, br = R >> 6;
        const int e = bb / (bc * br);
        const int rem = bb - e * bc * br;
        const int rt = rem / bc, ct = rem - rt * bc;
        {
            const int r = t >> 2, c4 = (t & 3) << 4;
            const float* src = in + ((size_t)e * R + rt * 64 + r) * C + ct * 64 + c4;
#pragma unroll
            for (int q = 0; q < 4; q++) {
                float4 f = ((const float4*)src)[q];
                tile[r][c4 + q * 4 + 0] = f.x;
                tile[r][c4 + q * 4 + 1] = f.y;
                tile[r][c4 + q * 4 + 2] = f.z;
                tile[r][c4 + q * 4 + 3] = f.w;
            }
        }
        __syncthreads();
        {
            const int c = t >> 2, r4 = (t & 3) << 4;
            u16x8 o0, o1;
#pragma unroll
            for (int j = 0; j < 8; j++)  o0[j] = f2bf(tile[r4 + j][c]);
#pragma unroll
            for (int j = 0; j < 8; j++)  o1[j] = f2bf(tile[r4 + 8 + j][c]);
            unsigned short* dst = outp + ((size_t)e * C + ct * 64 + c) * R + rt * 64 + r4;
            *(u16x8*)dst       = o0;
            *(u16x8*)(dst + 8) = o1;
        }
        return;
    }

    const int wid = t >> 6, lane = t & 63;
    const int tok = (b - 9216) * 4 + wid;
    const size_t base = (size_t)tok * DIM;

    float4 v[3];
#pragma unroll
    for (int j = 0; j < 3; j++)
        v[j] = *(const float4*)(x + base + lane * 4 + j * 256);
    float ss = 0.f;
#pragma unroll
    for (int j = 0; j < 3; j++)
        ss += v[j].x * v[j].x + v[j].y * v[j].y + v[j].z * v[j].z + v[j].w * v[j].w;
#pragma unroll
    for (int s = 32; s > 0; s >>= 1) ss += __shfl_xor(ss, s);
    const float rstd = rsqrtf(ss * (1.0f / DIM) + EPSV);

    float rp[8];
#pragma unroll
    for (int e = 0; e < 8; e++) rp[e] = 0.f;
#pragma unroll
    for (int j = 0; j < 3; j++) {
        float4 lw = *(const float4*)(lnw + lane * 4 + j * 256);
        float xv[4] = { v[j].x * rstd * lw.x, v[j].y * rstd * lw.y,
                        v[j].z * rstd * lw.z, v[j].w * rstd * lw.w };
        u16x4 pk = { f2bf(xv[0]), f2bf(xv[1]), f2bf(xv[2]), f2bf(xv[3]) };
        *(u16x4*)(xn + base + lane * 4 + j * 256) = pk;
#pragma unroll
        for (int i = 0; i < 4; i++) {
            const int d = lane * 4 + j * 256 + i;
            const float4* rr = (const float4*)(rw + (size_t)d * 8);
            float4 a = rr[0], bq = rr[1];
            rp[0] += xv[i] * a.x;  rp[1] += xv[i] * a.y;
            rp[2] += xv[i] * a.z;  rp[3] += xv[i] * a.w;
            rp[4] += xv[i] * bq.x; rp[5] += xv[i] * bq.y;
            rp[6] += xv[i] * bq.z; rp[7] += xv[i] * bq.w;
        }
    }
#pragma unroll
    for (int s = 32; s > 0; s >>= 1) {
#pragma unroll
        for (int e = 0; e < 8; e++) rp[e] += __shfl_xor(rp[e], s);
    }
    if (lane == 0) {
        float m = -1e30f; int am = 0;
#pragma unroll
        for (int e = 0; e < 8; e++) {
            out_logits[(size_t)tok * 8 + e] = rp[e];
            if (rp[e] > m) { m = rp[e]; am = e; }
        }
        float se = 0.f;
#pragma unroll
        for (int e = 0; e < 8; e++) se += expf(rp[e] - m);
        topp[tok] = 1.0f / se;
        out_eidx[tok] = (float)am;
        eidx[tok] = am;
    }
}

// ---------------------------------------------------------------------------
__global__ __launch_bounds__(256) void k_hist(
    const int* __restrict__ eidx, int* __restrict__ blkhist)
{
    __shared__ int h[8];
    if (threadIdx.x < 8) h[threadIdx.x] = 0;
    __syncthreads();
    atomicAdd(&h[eidx[blockIdx.x * 256 + threadIdx.x]], 1);
    __syncthreads();
    if (threadIdx.x < 8) blkhist[blockIdx.x * 8 + threadIdx.x] = h[threadIdx.x];
}

// ---------------------------------------------------------------------------
__global__ __launch_bounds__(512) void k_prefix(
    const int* __restrict__ blkhist, int* __restrict__ base,
    int* __restrict__ cnt)
{
    __shared__ int h[64 * 8];
    __shared__ int tot[8];
    __shared__ int eb[8];
    const int t = threadIdx.x;
    h[t] = blkhist[t];
    __syncthreads();
    const int b = t >> 3, e = t & 7;
    int s = 0;
    for (int bb = 0; bb < b; bb++) s += h[bb * 8 + e];
    if (b == 63) tot[e] = s + h[63 * 8 + e];
    __syncthreads();
    if (t == 0) {
        int p = 0;
#pragma unroll
        for (int q = 0; q < 8; q++) { eb[q] = p; p += tot[q]; }
    }
    __syncthreads();
    base[t] = eb[e] + s;
    if (t < 8) cnt[t] = tot[t];
}

// ---------------------------------------------------------------------------
__global__ __launch_bounds__(256) void k_scatter(
    const int* __restrict__ eidx, const int* __restrict__ base,
    int* __restrict__ list)
{
    __shared__ int wcnt[4][8];
    __shared__ int bb[8];
    const int t = threadIdx.x, b = blockIdx.x;
    const int lane = t & 63, wid = t >> 6;
    if (t < 8) bb[t] = base[b * 8 + t];
    const int tok = b * 256 + t;
    const int e = eidx[tok];
    int wrank = 0;
#pragma unroll
    for (int q = 0; q < 8; q++) {
        unsigned long long m = __ballot(e == q);
        if (e == q) wrank = __popcll(m & ((1ull << lane) - 1ull));
        if (lane == 0) wcnt[wid][q] = __popcll(m);
    }
    __syncthreads();
    int wbase = 0;
#pragma unroll
    for (int w = 0; w < 4; w++)
        if (w < wid) wbase += wcnt[w][e];
    list[bb[e] + wbase + wrank] = tok;
}

// ---------------------------------------------------------------------------
// Big grouped GEMM: 256x256 tile, BK=64, 512 threads / 8 waves (2Mx4N, wave
// tile 128x64), DOUBLE-buffered LDS (128 KB, 1 block/CU), stage(t+1) issued
// before compute(t), ONE barrier per K-tile whose vmcnt0 drain covers loads
// issued a full K-tile (~2300cy of MFMA+ds_read) earlier -> latency hidden.
// Addressing (XOR chunk swizzle / fragment phys / epilogues) carried over
// unchanged from the R3-proven kernels.
// MODE 0: Hperm[dense,:] = relu(Xn[tok,:] @ WiT)   (A gathered via list)
// MODE 1: out[tok,:] = hs + topp*(Hperm[dense,:] @ WoT)  (A dense rows)
// ---------------------------------------------------------------------------
template<int MODE>
__global__ __launch_bounds__(512, 2) void k_gemmB(
    const unsigned short* __restrict__ A, const unsigned short* __restrict__ Bw,
    const int* __restrict__ list, const int* __restrict__ cnt,
    unsigned short* __restrict__ Hout,
    const float* __restrict__ hs, const float* __restrict__ topp,
    float* __restrict__ out)
{
    constexpr int K   = (MODE == 0) ? DIM : FFD;
    constexpr int N   = (MODE == 0) ? FFD : DIM;
    constexpr int TNT = N / 256;                  // 12 / 3
    constexpr int NT  = K / 64;                   // 12 / 48
    __shared__ unsigned short As[2][256 * 64];    // 2 x 32 KB
    __shared__ unsigned short Bs[2][256 * 64];    // 2 x 32 KB
    __shared__ int tokrow[256];
    __shared__ int spref[9];
    __shared__ int ebase[8];

    const int t = threadIdx.x, lane = t & 63, wid = t >> 6;
    if (t == 0) {
        int p = 0, qq = 0;
        spref[0] = 0;
#pragma unroll
        for (int e = 0; e < 8; e++) {
            ebase[e] = qq; qq += cnt[e];
            p += (cnt[e] + 255) >> 8;
            spref[e + 1] = p;
        }
    }
    __syncthreads();
    const int total = spref[8] * TNT;
    const int moff = (wid >> 2) * 128;            // wave row block (2)
    const int noff = (wid & 3) * 64;              // wave col block (4)
    const int lr = lane & 15, lq = lane >> 4;

    // bijective XCD swizzle
    const int nwg = gridDim.x;
    const int xcd = blockIdx.x & 7, rr8 = blockIdx.x >> 3;
    const int qd = nwg >> 3, rm = nwg & 7;
    const int bid = (xcd < rm ? xcd * (qd + 1) : rm * (qd + 1) + (xcd - rm) * qd) + rr8;

    // staging chunk geometry: 2048 16B-chunks per 256x64 tile, 4 per thread.
    // chunk c -> row c>>3, slot (c&7)^(row&7)  [XOR swizzle, both sides]
    int crow[4], csub[4];
#pragma unroll
    for (int i = 0; i < 4; i++) {
        int c = (wid * 4 + i) * 64 + lane;
        crow[i] = c >> 3;
        csub[i] = (c & 7) ^ (crow[i] & 7);
    }

    for (int w = bid; w < total; w += gridDim.x) {
        const int gm = w / TNT, tn = w - gm * TNT;
        int e = 0;
        while (gm >= spref[e + 1]) e++;
        const int ce = cnt[e], eb = ebase[e];
        const int m0 = (gm - spref[e]) * 256, n0 = tn * 256;

        __syncthreads();                  // protect tokrow vs prior epilogue
        if (t < 256)
            tokrow[t] = (m0 + t < ce) ? list[eb + m0 + t] : list[eb];
        __syncthreads();

        const unsigned short* aP[4];
        const unsigned short* bP[4];
#pragma unroll
        for (int i = 0; i < 4; i++) {
            if (MODE == 0) {
                aP[i] = A + (size_t)tokrow[crow[i]] * K + csub[i] * 8;
            } else {
                const int drow = (m0 + crow[i] < ce) ? (m0 + crow[i]) : (ce - 1);
                aP[i] = A + (size_t)(eb + drow) * K + csub[i] * 8;
            }
            bP[i] = Bw + ((size_t)e * N + n0 + crow[i]) * K + csub[i] * 8;
        }

        f32x4 acc[8][4];
#pragma unroll
        for (int mi = 0; mi < 8; mi++)
#pragma unroll
            for (int ni = 0; ni < 4; ni++) acc[mi][ni] = (f32x4){0, 0, 0, 0};

        // prologue: stage K-tile 0 into buffer 0
#pragma unroll
        for (int i = 0; i < 4; i++) {
            gload16(aP[i], &As[0][(wid * 4 + i) * 512]);
            gload16(bP[i], &Bs[0][(wid * 4 + i) * 512]);
        }

        for (int kt = 0; kt < NT; ++kt) {
            const int cur = kt & 1;
            __syncthreads();   // drains buf[cur] stages (issued 1 K-tile ago);
                               // all waves done reading buf[cur^1]
            if (kt + 1 < NT) {
                const int k0n = (kt + 1) * 64;
#pragma unroll
                for (int i = 0; i < 4; i++) {
                    gload16(aP[i] + k0n, &As[cur ^ 1][(wid * 4 + i) * 512]);
                    gload16(bP[i] + k0n, &Bs[cur ^ 1][(wid * 4 + i) * 512]);
                }
            }
            __builtin_amdgcn_s_setprio(1);
#pragma unroll
            for (int kf = 0; kf < 2; kf++) {
                const int phys = ((kf * 4 + lq) ^ (lr & 7)) * 8;
                bf16x8 af[8], bfr[4];
#pragma unroll
                for (int mi = 0; mi < 8; mi++)
                    af[mi] = as_bf(*(const u16x8*)&As[cur][(moff + mi * 16 + lr) * 64 + phys]);
#pragma unroll
                for (int ni = 0; ni < 4; ni++)
                    bfr[ni] = as_bf(*(const u16x8*)&Bs[cur][(noff + ni * 16 + lr) * 64 + phys]);
#pragma unroll
                for (int mi = 0; mi < 8; mi++)
#pragma unroll
                    for (int ni = 0; ni < 4; ni++)
                        acc[mi][ni] = __builtin_amdgcn_mfma_f32_16x16x32_bf16(
                            af[mi], bfr[ni], acc[mi][ni], 0, 0, 0);
            }
            __builtin_amdgcn_s_setprio(0);
        }

        // epilogue
#pragma unroll
        for (int mi = 0; mi < 8; mi++) {
#pragma unroll
            for (int r4 = 0; r4 < 4; r4++) {
                const int row = moff + mi * 16 + lq * 4 + r4;
                if (m0 + row < ce) {
                    if (MODE == 0) {
                        unsigned short* hp = Hout + (size_t)(eb + m0 + row) * FFD + n0 + noff;
#pragma unroll
                        for (int ni = 0; ni < 4; ni++) {
                            float v = acc[mi][ni][r4];
                            v = v > 0.f ? v : 0.f;
                            hp[ni * 16 + lr] = f2bf(v);
                        }
                    } else {
                        const int tok = tokrow[row];
                        const float tp = topp[tok];
#pragma unroll
                        for (int ni = 0; ni < 4; ni++) {
                            const size_t idx = (size_t)tok * DIM + n0 + noff + ni * 16 + lr;
                            out[idx] = hs[idx] + tp * acc[mi][ni][r4];
                        }
                    }
                }
            }
        }
    }
}

// ---------------------------------------------------------------------------
extern "C" void kernel_launch(void* const* d_in, const int* in_sizes, int n_in,
                              void* d_out, int out_size, void* d_ws, size_t ws_size,
                              hipStream_t stream)
{
    const float* hs  = (const float*)d_in[0];
    const float* lnw = (const float*)d_in[1];
    const float* rw  = (const float*)d_in[2];
    const float* wi  = (const float*)d_in[3];
    const float* wo  = (const float*)d_in[4];

    float* out        = (float*)d_out;
    float* out_logits = out + (size_t)N_TOK * DIM;
    float* out_eidx   = out_logits + (size_t)N_TOK * NEXP;

    char* ws = (char*)d_ws;
    size_t off = 0;
    int*   cnt     = (int*)(ws + off);         off += 256;
    int*   list    = (int*)(ws + off);         off += (size_t)N_TOK * 4;
    float* topp    = (float*)(ws + off);       off += (size_t)N_TOK * 4;
    int*   eidx    = (int*)(ws + off);         off += (size_t)N_TOK * 4;
    int*   blkhist = (int*)(ws + off);         off += 4096;
    int*   base    = (int*)(ws + off);         off += 4096;
    unsigned short* xn  = (unsigned short*)(ws + off); off += (size_t)N_TOK * DIM * 2;
    unsigned short* Hb  = (unsigned short*)(ws + off); off += (size_t)N_TOK * FFD * 2;
    unsigned short* wob = (unsigned short*)(ws + off);

    // wi^T (bf16 [e][F][D]) lives in d_out's first 37.75 MB: dead before
    // GEMM2's epilogue writes `out`.
    unsigned short* wib = (unsigned short*)d_out;

    k_setup<<<13312, 256, 0, stream>>>(wi, wib, wo, wob, hs, lnw, rw,
                                       out_logits, out_eidx, topp, eidx, xn);
    k_hist<<<64, 256, 0, stream>>>(eidx, blkhist);
    k_prefix<<<1, 512, 0, stream>>>(blkhist, base, cnt);
    k_scatter<<<64, 256, 0, stream>>>(eidx, base, list);
    k_gemmB<0><<<256, 512, 0, stream>>>(xn, wib, list, cnt, Hb,
                                        nullptr, nullptr, nullptr);
    k_gemmB<1><<<256, 512, 0, stream>>>(Hb, wob, list, cnt, nullptr,
                                        hs, topp, out);
}

// Round 10
// 344.181 us; speedup vs baseline: 1.0009x; 1.0009x over previous
//
#include <hip/hip_runtime.h>
#include <math.h>

#define N_TOK 16384
#define DIM   768
#define FFD   3072
#define NEXP  8
#define EPSV  1e-6f

typedef __attribute__((ext_vector_type(4))) float f32x4;
typedef __attribute__((ext_vector_type(4))) unsigned short u16x4;
typedef __attribute__((ext_vector_type(8))) unsigned short u16x8;
typedef __attribute__((ext_vector_type(8))) __bf16 bf16x8;

static __device__ __forceinline__ unsigned short f2bf(float f) {
    unsigned int u = __builtin_bit_cast(unsigned int, f);
    u += 0x7fffu + ((u >> 16) & 1u);   // round-to-nearest-even
    return (unsigned short)(u >> 16);
}
static __device__ __forceinline__ bf16x8 as_bf(u16x8 v) {
    return __builtin_bit_cast(bf16x8, v);
}
static __device__ __forceinline__ void gload16(const void* g, void* l) {
    __builtin_amdgcn_global_load_lds(
        (const __attribute__((address_space(1))) unsigned int*)g,
        (__attribute__((address_space(3))) unsigned int*)l, 16, 0, 0);
}

// ---------------------------------------------------------------------------
// Fused setup kernel: blocks [0,4608) convert wi, [4608,9216) convert wo,
// [9216,13312) run RMSNorm+router. Transpose tile stride 65 (was 68):
// 65 % 32 == 1 -> both write banks (r + 16c') and read banks (16c'+j+r)
// are 2-way across the wave = conflict-free (R8 measured 4.7M conflicts
// at stride 68: +68B/row = +4 banks -> 8-way).
// ---------------------------------------------------------------------------
__global__ __launch_bounds__(256) void k_setup(
    const float* __restrict__ wi, unsigned short* __restrict__ wib,
    const float* __restrict__ wo, unsigned short* __restrict__ wob,
    const float* __restrict__ x, const float* __restrict__ lnw,
    const float* __restrict__ rw,
    float* __restrict__ out_logits, float* __restrict__ out_eidx,
    float* __restrict__ topp, int* __restrict__ eidx,
    unsigned short* __restrict__ xn)
{
    __shared__ float tile[64][65];
    const int t = threadIdx.x;
    const int b = blockIdx.x;

    if (b < 9216) {
        const float* in;
        unsigned short* outp;
        int R, C, bb;
        if (b < 4608) { in = wi; outp = wib; R = DIM; C = FFD; bb = b; }
        else          { in = wo; outp = wob; R = FFD; C = DIM; bb = b - 4608; }
        const int bc = C >> 6, br = R >> 6;
        const int e = bb / (bc * br);
        const int rem = bb - e * bc * br;
        const int rt = rem / bc, ct = rem - rt * bc;
        {
            const int r = t >> 2, c4 = (t & 3) << 4;
            const float* src = in + ((size_t)e * R + rt * 64 + r) * C + ct * 64 + c4;
#pragma unroll
            for (int q = 0; q < 4; q++) {
                float4 f = ((const float4*)src)[q];
                tile[r][c4 + q * 4 + 0] = f.x;
                tile[r][c4 + q * 4 + 1] = f.y;
                tile[r][c4 + q * 4 + 2] = f.z;
                tile[r][c4 + q * 4 + 3] = f.w;
            }
        }
        __syncthreads();
        {
            const int c = t >> 2, r4 = (t & 3) << 4;
            u16x8 o0, o1;
#pragma unroll
            for (int j = 0; j < 8; j++)  o0[j] = f2bf(tile[r4 + j][c]);
#pragma unroll
            for (int j = 0; j < 8; j++)  o1[j] = f2bf(tile[r4 + 8 + j][c]);
            unsigned short* dst = outp + ((size_t)e * C + ct * 64 + c) * R + rt * 64 + r4;
            *(u16x8*)dst       = o0;
            *(u16x8*)(dst + 8) = o1;
        }
        return;
    }

    const int wid = t >> 6, lane = t & 63;
    const int tok = (b - 9216) * 4 + wid;
    const size_t base = (size_t)tok * DIM;

    float4 v[3];
#pragma unroll
    for (int j = 0; j < 3; j++)
        v[j] = *(const float4*)(x + base + lane * 4 + j * 256);
    float ss = 0.f;
#pragma unroll
    for (int j = 0; j < 3; j++)
        ss += v[j].x * v[j].x + v[j].y * v[j].y + v[j].z * v[j].z + v[j].w * v[j].w;
#pragma unroll
    for (int s = 32; s > 0; s >>= 1) ss += __shfl_xor(ss, s);
    const float rstd = rsqrtf(ss * (1.0f / DIM) + EPSV);

    float rp[8];
#pragma unroll
    for (int e = 0; e < 8; e++) rp[e] = 0.f;
#pragma unroll
    for (int j = 0; j < 3; j++) {
        float4 lw = *(const float4*)(lnw + lane * 4 + j * 256);
        float xv[4] = { v[j].x * rstd * lw.x, v[j].y * rstd * lw.y,
                        v[j].z * rstd * lw.z, v[j].w * rstd * lw.w };
        u16x4 pk = { f2bf(xv[0]), f2bf(xv[1]), f2bf(xv[2]), f2bf(xv[3]) };
        *(u16x4*)(xn + base + lane * 4 + j * 256) = pk;
#pragma unroll
        for (int i = 0; i < 4; i++) {
            const int d = lane * 4 + j * 256 + i;
            const float4* rr = (const float4*)(rw + (size_t)d * 8);
            float4 a = rr[0], bq = rr[1];
            rp[0] += xv[i] * a.x;  rp[1] += xv[i] * a.y;
            rp[2] += xv[i] * a.z;  rp[3] += xv[i] * a.w;
            rp[4] += xv[i] * bq.x; rp[5] += xv[i] * bq.y;
            rp[6] += xv[i] * bq.z; rp[7] += xv[i] * bq.w;
        }
    }
#pragma unroll
    for (int s = 32; s > 0; s >>= 1) {
#pragma unroll
        for (int e = 0; e < 8; e++) rp[e] += __shfl_xor(rp[e], s);
    }
    if (lane == 0) {
        float m = -1e30f; int am = 0;
#pragma unroll
        for (int e = 0; e < 8; e++) {
            out_logits[(size_t)tok * 8 + e] = rp[e];
            if (rp[e] > m) { m = rp[e]; am = e; }
        }
        float se = 0.f;
#pragma unroll
        for (int e = 0; e < 8; e++) se += expf(rp[e] - m);
        topp[tok] = 1.0f / se;
        out_eidx[tok] = (float)am;
        eidx[tok] = am;
    }
}

// ---------------------------------------------------------------------------
__global__ __launch_bounds__(256) void k_hist(
    const int* __restrict__ eidx, int* __restrict__ blkhist)
{
    __shared__ int h[8];
    if (threadIdx.x < 8) h[threadIdx.x] = 0;
    __syncthreads();
    atomicAdd(&h[eidx[blockIdx.x * 256 + threadIdx.x]], 1);
    __syncthreads();
    if (threadIdx.x < 8) blkhist[blockIdx.x * 8 + threadIdx.x] = h[threadIdx.x];
}

// ---------------------------------------------------------------------------
__global__ __launch_bounds__(512) void k_prefix(
    const int* __restrict__ blkhist, int* __restrict__ base,
    int* __restrict__ cnt)
{
    __shared__ int h[64 * 8];
    __shared__ int tot[8];
    __shared__ int eb[8];
    const int t = threadIdx.x;
    h[t] = blkhist[t];
    __syncthreads();
    const int b = t >> 3, e = t & 7;
    int s = 0;
    for (int bb = 0; bb < b; bb++) s += h[bb * 8 + e];
    if (b == 63) tot[e] = s + h[63 * 8 + e];
    __syncthreads();
    if (t == 0) {
        int p = 0;
#pragma unroll
        for (int q = 0; q < 8; q++) { eb[q] = p; p += tot[q]; }
    }
    __syncthreads();
    base[t] = eb[e] + s;
    if (t < 8) cnt[t] = tot[t];
}

// ---------------------------------------------------------------------------
__global__ __launch_bounds__(256) void k_scatter(
    const int* __restrict__ eidx, const int* __restrict__ base,
    int* __restrict__ list)
{
    __shared__ int wcnt[4][8];
    __shared__ int bb[8];
    const int t = threadIdx.x, b = blockIdx.x;
    const int lane = t & 63, wid = t >> 6;
    if (t < 8) bb[t] = base[b * 8 + t];
    const int tok = b * 256 + t;
    const int e = eidx[tok];
    int wrank = 0;
#pragma unroll
    for (int q = 0; q < 8; q++) {
        unsigned long long m = __ballot(e == q);
        if (e == q) wrank = __popcll(m & ((1ull << lane) - 1ull));
        if (lane == 0) wcnt[wid][q] = __popcll(m);
    }
    __syncthreads();
    int wbase = 0;
#pragma unroll
    for (int w = 0; w < 4; w++)
        if (w < wid) wbase += wcnt[w][e];
    list[bb[e] + wbase + wrank] = tok;
}

// ---------------------------------------------------------------------------
// Grouped GEMM, m97 geometry: 128x128 tile, BK=64, single-buffer 2-barrier,
// 4 waves (2x2, wave tile 64x64), 32KB LDS, __launch_bounds__(256,3) ->
// 3-4 blocks/CU. The barrier drain of one block hides under the other
// blocks' MFMAs (m114 TLP mechanism) — prior rounds capped this at 2.
// MODE 0: Hperm[dense,:] = relu(Xn[tok,:] @ WiT)   (A gathered via list)
// MODE 1: out[tok,:] = hs + topp*(Hperm[dense,:] @ WoT)  (A dense rows)
// ---------------------------------------------------------------------------
template<int MODE>
__global__ __launch_bounds__(256, 3) void k_gemm(
    const unsigned short* __restrict__ A, const unsigned short* __restrict__ Bw,
    const int* __restrict__ list, const int* __restrict__ cnt,
    unsigned short* __restrict__ Hout,
    const float* __restrict__ hs, const float* __restrict__ topp,
    float* __restrict__ out)
{
    constexpr int K   = (MODE == 0) ? DIM : FFD;
    constexpr int N   = (MODE == 0) ? FFD : DIM;
    constexpr int TNT = N / 128;                  // 24 / 6
    __shared__ unsigned short Asm[128 * 64];      // 16 KB
    __shared__ unsigned short Bsm[128 * 64];      // 16 KB
    __shared__ int tokrow[128];
    __shared__ int spref[9];
    __shared__ int ebase[8];

    const int t = threadIdx.x, lane = t & 63, wid = t >> 6;
    if (t == 0) {
        int p = 0, qq = 0;
        spref[0] = 0;
#pragma unroll
        for (int e = 0; e < 8; e++) {
            ebase[e] = qq; qq += cnt[e];
            p += (cnt[e] + 127) >> 7;
            spref[e + 1] = p;
        }
    }
    __syncthreads();
    const int total = spref[8] * TNT;
    const int moff = (wid >> 1) * 64, noff = (wid & 1) * 64;
    const int lr = lane & 15, lq = lane >> 4;

    // bijective XCD swizzle: consecutive tiles (same A m-tile) -> same XCD
    const int nwg = gridDim.x;
    const int xcd = blockIdx.x & 7, rr8 = blockIdx.x >> 3;
    const int qd = nwg >> 3, rm = nwg & 7;
    const int bid = (xcd < rm ? xcd * (qd + 1) : rm * (qd + 1) + (xcd - rm) * qd) + rr8;

    // staging chunk geometry: 1024 16B-chunks per 128x64 tile, 4 per thread.
    // chunk c -> row c>>3, slot (c&7)^(row&7)  [XOR swizzle, both sides]
    int crow[4], csub[4];
#pragma unroll
    for (int i = 0; i < 4; i++) {
        int c = (wid * 4 + i) * 64 + lane;
        crow[i] = c >> 3;
        csub[i] = (c & 7) ^ (crow[i] & 7);
    }

    for (int w = bid; w < total; w += gridDim.x) {
        const int gm = w / TNT, tn = w - gm * TNT;
        int e = 0;
        while (gm >= spref[e + 1]) e++;
        const int ce = cnt[e], eb = ebase[e];
        const int m0 = (gm - spref[e]) * 128, n0 = tn * 128;

        __syncthreads();
        if (t < 128)
            tokrow[t] = (m0 + t < ce) ? list[eb + m0 + t] : list[eb];
        __syncthreads();

        const unsigned short* aP[4];
        const unsigned short* bP[4];
#pragma unroll
        for (int i = 0; i < 4; i++) {
            if (MODE == 0) {
                aP[i] = A + (size_t)tokrow[crow[i]] * K + csub[i] * 8;
            } else {
                const int drow = (m0 + crow[i] < ce) ? (m0 + crow[i]) : (ce - 1);
                aP[i] = A + (size_t)(eb + drow) * K + csub[i] * 8;
            }
            bP[i] = Bw + ((size_t)e * N + n0 + crow[i]) * K + csub[i] * 8;
        }

        f32x4 acc[4][4];
#pragma unroll
        for (int mi = 0; mi < 4; mi++)
#pragma unroll
            for (int ni = 0; ni < 4; ni++) acc[mi][ni] = (f32x4){0, 0, 0, 0};

        for (int k0 = 0; k0 < K; k0 += 64) {
#pragma unroll
            for (int i = 0; i < 4; i++) {
                gload16(aP[i] + k0, Asm + (wid * 4 + i) * 512);
                gload16(bP[i] + k0, Bsm + (wid * 4 + i) * 512);
            }
            __syncthreads();
#pragma unroll
            for (int kf = 0; kf < 2; kf++) {
                const int phys = ((kf * 4 + lq) ^ (lr & 7)) * 8;
                bf16x8 af[4], bfr[4];
#pragma unroll
                for (int mi = 0; mi < 4; mi++)
                    af[mi] = as_bf(*(const u16x8*)&Asm[(moff + mi * 16 + lr) * 64 + phys]);
#pragma unroll
                for (int ni = 0; ni < 4; ni++)
                    bfr[ni] = as_bf(*(const u16x8*)&Bsm[(noff + ni * 16 + lr) * 64 + phys]);
#pragma unroll
                for (int mi = 0; mi < 4; mi++)
#pragma unroll
                    for (int ni = 0; ni < 4; ni++)
                        acc[mi][ni] = __builtin_amdgcn_mfma_f32_16x16x32_bf16(
                            af[mi], bfr[ni], acc[mi][ni], 0, 0, 0);
            }
            __syncthreads();
        }

        // epilogue
#pragma unroll
        for (int mi = 0; mi < 4; mi++) {
#pragma unroll
            for (int r4 = 0; r4 < 4; r4++) {
                const int row = moff + mi * 16 + lq * 4 + r4;
                if (m0 + row < ce) {
                    if (MODE == 0) {
                        unsigned short* hp = Hout + (size_t)(eb + m0 + row) * FFD + n0 + noff;
#pragma unroll
                        for (int ni = 0; ni < 4; ni++) {
                            float v = acc[mi][ni][r4];
                            v = v > 0.f ? v : 0.f;
                            hp[ni * 16 + lr] = f2bf(v);
                        }
                    } else {
                        const int tok = tokrow[row];
                        const float tp = topp[tok];
#pragma unroll
                        for (int ni = 0; ni < 4; ni++) {
                            const size_t idx = (size_t)tok * DIM + n0 + noff + ni * 16 + lr;
                            out[idx] = hs[idx] + tp * acc[mi][ni][r4];
                        }
                    }
                }
            }
        }
    }
}

// ---------------------------------------------------------------------------
extern "C" void kernel_launch(void* const* d_in, const int* in_sizes, int n_in,
                              void* d_out, int out_size, void* d_ws, size_t ws_size,
                              hipStream_t stream)
{
    const float* hs  = (const float*)d_in[0];
    const float* lnw = (const float*)d_in[1];
    const float* rw  = (const float*)d_in[2];
    const float* wi  = (const float*)d_in[3];
    const float* wo  = (const float*)d_in[4];

    float* out        = (float*)d_out;
    float* out_logits = out + (size_t)N_TOK * DIM;
    float* out_eidx   = out_logits + (size_t)N_TOK * NEXP;

    char* ws = (char*)d_ws;
    size_t off = 0;
    int*   cnt     = (int*)(ws + off);         off += 256;
    int*   list    = (int*)(ws + off);         off += (size_t)N_TOK * 4;
    float* topp    = (float*)(ws + off);       off += (size_t)N_TOK * 4;
    int*   eidx    = (int*)(ws + off);         off += (size_t)N_TOK * 4;
    int*   blkhist = (int*)(ws + off);         off += 4096;
    int*   base    = (int*)(ws + off);         off += 4096;
    unsigned short* xn  = (unsigned short*)(ws + off); off += (size_t)N_TOK * DIM * 2;
    unsigned short* Hb  = (unsigned short*)(ws + off); off += (size_t)N_TOK * FFD * 2;
    unsigned short* wob = (unsigned short*)(ws + off);

    // wi^T (bf16 [e][F][D]) lives in d_out's first 37.75 MB: dead before
    // GEMM2's epilogue writes `out`.
    unsigned short* wib = (unsigned short*)d_out;

    k_setup<<<13312, 256, 0, stream>>>(wi, wib, wo, wob, hs, lnw, rw,
                                       out_logits, out_eidx, topp, eidx, xn);
    k_hist<<<64, 256, 0, stream>>>(eidx, blkhist);
    k_prefix<<<1, 512, 0, stream>>>(blkhist, base, cnt);
    k_scatter<<<64, 256, 0, stream>>>(eidx, base, list);
    k_gemm<0><<<3072, 256, 0, stream>>>(xn, wib, list, cnt, Hb,
                                        nullptr, nullptr, nullptr);
    k_gemm<1><<<816, 256, 0, stream>>>(Hb, wob, list, cnt, nullptr,
                                       hs, topp, out);
}

// Round 11
// 303.312 us; speedup vs baseline: 1.1358x; 1.1347x over previous
//
#include <hip/hip_runtime.h>
#include <math.h>

#define N_TOK 16384
#define DIM   768
#define FFD   3072
#define NEXP  8
#define EPSV  1e-6f

typedef __attribute__((ext_vector_type(4))) float f32x4;
typedef __attribute__((ext_vector_type(4))) unsigned short u16x4;
typedef __attribute__((ext_vector_type(8))) unsigned short u16x8;
typedef __attribute__((ext_vector_type(8))) __bf16 bf16x8;

static __device__ __forceinline__ unsigned short f2bf(float f) {
    unsigned int u = __builtin_bit_cast(unsigned int, f);
    u += 0x7fffu + ((u >> 16) & 1u);   // round-to-nearest-even
    return (unsigned short)(u >> 16);
}
static __device__ __forceinline__ bf16x8 as_bf(u16x8 v) {
    return __builtin_bit_cast(bf16x8, v);
}
static __device__ __forceinline__ void gload16(const void* g, void* l) {
    __builtin_amdgcn_global_load_lds(
        (const __attribute__((address_space(1))) unsigned int*)g,
        (__attribute__((address_space(3))) unsigned int*)l, 16, 0, 0);
}

// ---------------------------------------------------------------------------
// Fused setup kernel: blocks [0,4608) convert wi, [4608,9216) convert wo,
// [9216,13312) run RMSNorm+router. Transpose tile stride 65: 65%32==1 ->
// write banks and read banks both 2-way = free (R8 measured 4.7M conflicts
// at stride 68; R10 confirmed the fix: setup ~124us -> ~54us).
// ---------------------------------------------------------------------------
__global__ __launch_bounds__(256) void k_setup(
    const float* __restrict__ wi, unsigned short* __restrict__ wib,
    const float* __restrict__ wo, unsigned short* __restrict__ wob,
    const float* __restrict__ x, const float* __restrict__ lnw,
    const float* __restrict__ rw,
    float* __restrict__ out_logits, float* __restrict__ out_eidx,
    float* __restrict__ topp, int* __restrict__ eidx,
    unsigned short* __restrict__ xn)
{
    __shared__ float tile[64][65];
    const int t = threadIdx.x;
    const int b = blockIdx.x;

    if (b < 9216) {
        const float* in;
        unsigned short* outp;
        int R, C, bb;
        if (b < 4608) { in = wi; outp = wib; R = DIM; C = FFD; bb = b; }
        else          { in = wo; outp = wob; R = FFD; C = DIM; bb = b - 4608; }
        const int bc = C >> 6, br = R >> 6;
        const int e = bb / (bc * br);
        const int rem = bb - e * bc * br;
        const int rt = rem / bc, ct = rem - rt * bc;
        {
            const int r = t >> 2, c4 = (t & 3) << 4;
            const float* src = in + ((size_t)e * R + rt * 64 + r) * C + ct * 64 + c4;
#pragma unroll
            for (int q = 0; q < 4; q++) {
                float4 f = ((const float4*)src)[q];
                tile[r][c4 + q * 4 + 0] = f.x;
                tile[r][c4 + q * 4 + 1] = f.y;
                tile[r][c4 + q * 4 + 2] = f.z;
                tile[r][c4 + q * 4 + 3] = f.w;
            }
        }
        __syncthreads();
        {
            const int c = t >> 2, r4 = (t & 3) << 4;
            u16x8 o0, o1;
#pragma unroll
            for (int j = 0; j < 8; j++)  o0[j] = f2bf(tile[r4 + j][c]);
#pragma unroll
            for (int j = 0; j < 8; j++)  o1[j] = f2bf(tile[r4 + 8 + j][c]);
            unsigned short* dst = outp + ((size_t)e * C + ct * 64 + c) * R + rt * 64 + r4;
            *(u16x8*)dst       = o0;
            *(u16x8*)(dst + 8) = o1;
        }
        return;
    }

    const int wid = t >> 6, lane = t & 63;
    const int tok = (b - 9216) * 4 + wid;
    const size_t base = (size_t)tok * DIM;

    float4 v[3];
#pragma unroll
    for (int j = 0; j < 3; j++)
        v[j] = *(const float4*)(x + base + lane * 4 + j * 256);
    float ss = 0.f;
#pragma unroll
    for (int j = 0; j < 3; j++)
        ss += v[j].x * v[j].x + v[j].y * v[j].y + v[j].z * v[j].z + v[j].w * v[j].w;
#pragma unroll
    for (int s = 32; s > 0; s >>= 1) ss += __shfl_xor(ss, s);
    const float rstd = rsqrtf(ss * (1.0f / DIM) + EPSV);

    float rp[8];
#pragma unroll
    for (int e = 0; e < 8; e++) rp[e] = 0.f;
#pragma unroll
    for (int j = 0; j < 3; j++) {
        float4 lw = *(const float4*)(lnw + lane * 4 + j * 256);
        float xv[4] = { v[j].x * rstd * lw.x, v[j].y * rstd * lw.y,
                        v[j].z * rstd * lw.z, v[j].w * rstd * lw.w };
        u16x4 pk = { f2bf(xv[0]), f2bf(xv[1]), f2bf(xv[2]), f2bf(xv[3]) };
        *(u16x4*)(xn + base + lane * 4 + j * 256) = pk;
#pragma unroll
        for (int i = 0; i < 4; i++) {
            const int d = lane * 4 + j * 256 + i;
            const float4* rr = (const float4*)(rw + (size_t)d * 8);
            float4 a = rr[0], bq = rr[1];
            rp[0] += xv[i] * a.x;  rp[1] += xv[i] * a.y;
            rp[2] += xv[i] * a.z;  rp[3] += xv[i] * a.w;
            rp[4] += xv[i] * bq.x; rp[5] += xv[i] * bq.y;
            rp[6] += xv[i] * bq.z; rp[7] += xv[i] * bq.w;
        }
    }
#pragma unroll
    for (int s = 32; s > 0; s >>= 1) {
#pragma unroll
        for (int e = 0; e < 8; e++) rp[e] += __shfl_xor(rp[e], s);
    }
    if (lane == 0) {
        float m = -1e30f; int am = 0;
#pragma unroll
        for (int e = 0; e < 8; e++) {
            out_logits[(size_t)tok * 8 + e] = rp[e];
            if (rp[e] > m) { m = rp[e]; am = e; }
        }
        float se = 0.f;
#pragma unroll
        for (int e = 0; e < 8; e++) se += expf(rp[e] - m);
        topp[tok] = 1.0f / se;
        out_eidx[tok] = (float)am;
        eidx[tok] = am;
    }
}

// ---------------------------------------------------------------------------
__global__ __launch_bounds__(256) void k_hist(
    const int* __restrict__ eidx, int* __restrict__ blkhist)
{
    __shared__ int h[8];
    if (threadIdx.x < 8) h[threadIdx.x] = 0;
    __syncthreads();
    atomicAdd(&h[eidx[blockIdx.x * 256 + threadIdx.x]], 1);
    __syncthreads();
    if (threadIdx.x < 8) blkhist[blockIdx.x * 8 + threadIdx.x] = h[threadIdx.x];
}

// ---------------------------------------------------------------------------
__global__ __launch_bounds__(512) void k_prefix(
    const int* __restrict__ blkhist, int* __restrict__ base,
    int* __restrict__ cnt)
{
    __shared__ int h[64 * 8];
    __shared__ int tot[8];
    __shared__ int eb[8];
    const int t = threadIdx.x;
    h[t] = blkhist[t];
    __syncthreads();
    const int b = t >> 3, e = t & 7;
    int s = 0;
    for (int bb = 0; bb < b; bb++) s += h[bb * 8 + e];
    if (b == 63) tot[e] = s + h[63 * 8 + e];
    __syncthreads();
    if (t == 0) {
        int p = 0;
#pragma unroll
        for (int q = 0; q < 8; q++) { eb[q] = p; p += tot[q]; }
    }
    __syncthreads();
    base[t] = eb[e] + s;
    if (t < 8) cnt[t] = tot[t];
}

// ---------------------------------------------------------------------------
__global__ __launch_bounds__(256) void k_scatter(
    const int* __restrict__ eidx, const int* __restrict__ base,
    int* __restrict__ list)
{
    __shared__ int wcnt[4][8];
    __shared__ int bb[8];
    const int t = threadIdx.x, b = blockIdx.x;
    const int lane = t & 63, wid = t >> 6;
    if (t < 8) bb[t] = base[b * 8 + t];
    const int tok = b * 256 + t;
    const int e = eidx[tok];
    int wrank = 0;
#pragma unroll
    for (int q = 0; q < 8; q++) {
        unsigned long long m = __ballot(e == q);
        if (e == q) wrank = __popcll(m & ((1ull << lane) - 1ull));
        if (lane == 0) wcnt[wid][q] = __popcll(m);
    }
    __syncthreads();
    int wbase = 0;
#pragma unroll
    for (int w = 0; w < 4; w++)
        if (w < wid) wbase += wcnt[w][e];
    list[bb[e] + wbase + wrank] = tok;
}

// ---------------------------------------------------------------------------
// GEMM1: 128x256 tile, BK=64, single-buffer 2-barrier (R8-proven ~82us),
// A gathered via token list, H written in dense (permuted) row order.
// ---------------------------------------------------------------------------
__global__ __launch_bounds__(256, 2) void k_gemm1(
    const unsigned short* __restrict__ A, const unsigned short* __restrict__ Bw,
    const int* __restrict__ list, const int* __restrict__ cnt,
    unsigned short* __restrict__ Hout)
{
    constexpr int K   = DIM;
    constexpr int N   = FFD;
    constexpr int TNT = N / 256;                  // 12
    __shared__ unsigned short Asm[128 * 64];      // 16 KB
    __shared__ unsigned short Bsm[256 * 64];      // 32 KB
    __shared__ int tokrow[128];
    __shared__ int spref[9];
    __shared__ int ebase[8];

    const int t = threadIdx.x, lane = t & 63, wid = t >> 6;
    if (t == 0) {
        int p = 0, qq = 0;
        spref[0] = 0;
#pragma unroll
        for (int e = 0; e < 8; e++) {
            ebase[e] = qq; qq += cnt[e];
            p += (cnt[e] + 127) >> 7;
            spref[e + 1] = p;
        }
    }
    __syncthreads();
    const int total = spref[8] * TNT;
    const int moff = (wid >> 1) * 64, noff = (wid & 1) * 128;
    const int lr = lane & 15, lq = lane >> 4;

    const int nwg = gridDim.x;
    const int xcd = blockIdx.x & 7, rr8 = blockIdx.x >> 3;
    const int qd = nwg >> 3, rm = nwg & 7;
    const int bid = (xcd < rm ? xcd * (qd + 1) : rm * (qd + 1) + (xcd - rm) * qd) + rr8;

    int arow[4], asub[4], brow[8], bsub[8];
#pragma unroll
    for (int i = 0; i < 4; i++) {
        int c = (wid * 4 + i) * 64 + lane;
        arow[i] = c >> 3;
        asub[i] = (c & 7) ^ (arow[i] & 7);
    }
#pragma unroll
    for (int i = 0; i < 8; i++) {
        int c = (wid * 8 + i) * 64 + lane;
        brow[i] = c >> 3;
        bsub[i] = (c & 7) ^ (brow[i] & 7);
    }

    for (int w = bid; w < total; w += gridDim.x) {
        const int gm = w / TNT, tn = w - gm * TNT;
        int e = 0;
        while (gm >= spref[e + 1]) e++;
        const int ce = cnt[e], eb = ebase[e];
        const int m0 = (gm - spref[e]) * 128, n0 = tn * 256;

        __syncthreads();
        if (t < 128)
            tokrow[t] = (m0 + t < ce) ? list[eb + m0 + t] : list[eb];
        __syncthreads();

        const unsigned short* aP[4];
        const unsigned short* bP[8];
#pragma unroll
        for (int i = 0; i < 4; i++)
            aP[i] = A + (size_t)tokrow[arow[i]] * K + asub[i] * 8;
#pragma unroll
        for (int i = 0; i < 8; i++)
            bP[i] = Bw + ((size_t)e * N + n0 + brow[i]) * K + bsub[i] * 8;

        f32x4 acc[4][8];
#pragma unroll
        for (int mi = 0; mi < 4; mi++)
#pragma unroll
            for (int ni = 0; ni < 8; ni++) acc[mi][ni] = (f32x4){0, 0, 0, 0};

        for (int k0 = 0; k0 < K; k0 += 64) {
#pragma unroll
            for (int i = 0; i < 4; i++)
                gload16(aP[i] + k0, Asm + (wid * 4 + i) * 512);
#pragma unroll
            for (int i = 0; i < 8; i++)
                gload16(bP[i] + k0, Bsm + (wid * 8 + i) * 512);
            __syncthreads();
#pragma unroll
            for (int kf = 0; kf < 2; kf++) {
                const int phys = ((kf * 4 + lq) ^ (lr & 7)) * 8;
                bf16x8 af[4], bfr[8];
#pragma unroll
                for (int mi = 0; mi < 4; mi++)
                    af[mi] = as_bf(*(const u16x8*)&Asm[(moff + mi * 16 + lr) * 64 + phys]);
#pragma unroll
                for (int ni = 0; ni < 8; ni++)
                    bfr[ni] = as_bf(*(const u16x8*)&Bsm[(noff + ni * 16 + lr) * 64 + phys]);
#pragma unroll
                for (int mi = 0; mi < 4; mi++)
#pragma unroll
                    for (int ni = 0; ni < 8; ni++)
                        acc[mi][ni] = __builtin_amdgcn_mfma_f32_16x16x32_bf16(
                            af[mi], bfr[ni], acc[mi][ni], 0, 0, 0);
            }
            __syncthreads();
        }

#pragma unroll
        for (int mi = 0; mi < 4; mi++) {
#pragma unroll
            for (int r4 = 0; r4 < 4; r4++) {
                const int row = moff + mi * 16 + lq * 4 + r4;
                if (m0 + row < ce) {
                    unsigned short* hp = Hout + (size_t)(eb + m0 + row) * FFD + n0 + noff;
#pragma unroll
                    for (int ni = 0; ni < 8; ni++) {
                        float v = acc[mi][ni][r4];
                        v = v > 0.f ? v : 0.f;
                        hp[ni * 16 + lr] = f2bf(v);
                    }
                }
            }
        }
    }
}

// ---------------------------------------------------------------------------
// GEMM2: 128x256 tile, BK=64, single-buffer 2-barrier (R8-proven ~82us),
// dense A rows from permuted H.
// out[tok,:] = hs[tok,:] + topp[tok]*(Hperm[denserow,:] @ WoT)
// ---------------------------------------------------------------------------
__global__ __launch_bounds__(256, 2) void k_gemm2(
    const unsigned short* __restrict__ A, const unsigned short* __restrict__ Bw,
    const int* __restrict__ list, const int* __restrict__ cnt,
    const float* __restrict__ hs, const float* __restrict__ topp,
    float* __restrict__ out)
{
    constexpr int K   = FFD;
    constexpr int N   = DIM;
    constexpr int TNT = N / 256;                  // 3
    __shared__ unsigned short Asm[128 * 64];      // 16 KB
    __shared__ unsigned short Bsm[256 * 64];      // 32 KB
    __shared__ int tokrow[128];
    __shared__ int spref[9];
    __shared__ int ebase[8];

    const int t = threadIdx.x, lane = t & 63, wid = t >> 6;
    if (t == 0) {
        int p = 0, qq = 0;
        spref[0] = 0;
#pragma unroll
        for (int e = 0; e < 8; e++) {
            ebase[e] = qq; qq += cnt[e];
            p += (cnt[e] + 127) >> 7;
            spref[e + 1] = p;
        }
    }
    __syncthreads();
    const int total = spref[8] * TNT;
    const int moff = (wid >> 1) * 64, noff = (wid & 1) * 128;
    const int lr = lane & 15, lq = lane >> 4;

    const int nwg = gridDim.x;
    const int xcd = blockIdx.x & 7, rr8 = blockIdx.x >> 3;
    const int qd = nwg >> 3, rm = nwg & 7;
    const int bid = (xcd < rm ? xcd * (qd + 1) : rm * (qd + 1) + (xcd - rm) * qd) + rr8;

    int arow[4], asub[4], brow[8], bsub[8];
#pragma unroll
    for (int i = 0; i < 4; i++) {
        int c = (wid * 4 + i) * 64 + lane;
        arow[i] = c >> 3;
        asub[i] = (c & 7) ^ (arow[i] & 7);
    }
#pragma unroll
    for (int i = 0; i < 8; i++) {
        int c = (wid * 8 + i) * 64 + lane;
        brow[i] = c >> 3;
        bsub[i] = (c & 7) ^ (brow[i] & 7);
    }

    for (int w = bid; w < total; w += gridDim.x) {
        const int gm = w / TNT, tn = w - gm * TNT;
        int e = 0;
        while (gm >= spref[e + 1]) e++;
        const int ce = cnt[e], eb = ebase[e];
        const int m0 = (gm - spref[e]) * 128, n0 = tn * 256;

        __syncthreads();
        if (t < 128)
            tokrow[t] = (m0 + t < ce) ? list[eb + m0 + t] : list[eb];
        __syncthreads();

        const unsigned short* aP[4];
        const unsigned short* bP[8];
#pragma unroll
        for (int i = 0; i < 4; i++) {
            const int drow = (m0 + arow[i] < ce) ? (m0 + arow[i]) : (ce - 1);
            aP[i] = A + (size_t)(eb + drow) * K + asub[i] * 8;
        }
#pragma unroll
        for (int i = 0; i < 8; i++)
            bP[i] = Bw + ((size_t)e * N + n0 + brow[i]) * K + bsub[i] * 8;

        f32x4 acc[4][8];
#pragma unroll
        for (int mi = 0; mi < 4; mi++)
#pragma unroll
            for (int ni = 0; ni < 8; ni++) acc[mi][ni] = (f32x4){0, 0, 0, 0};

        for (int k0 = 0; k0 < K; k0 += 64) {
#pragma unroll
            for (int i = 0; i < 4; i++)
                gload16(aP[i] + k0, Asm + (wid * 4 + i) * 512);
#pragma unroll
            for (int i = 0; i < 8; i++)
                gload16(bP[i] + k0, Bsm + (wid * 8 + i) * 512);
            __syncthreads();
#pragma unroll
            for (int kf = 0; kf < 2; kf++) {
                const int phys = ((kf * 4 + lq) ^ (lr & 7)) * 8;
                bf16x8 af[4], bfr[8];
#pragma unroll
                for (int mi = 0; mi < 4; mi++)
                    af[mi] = as_bf(*(const u16x8*)&Asm[(moff + mi * 16 + lr) * 64 + phys]);
#pragma unroll
                for (int ni = 0; ni < 8; ni++)
                    bfr[ni] = as_bf(*(const u16x8*)&Bsm[(noff + ni * 16 + lr) * 64 + phys]);
#pragma unroll
                for (int mi = 0; mi < 4; mi++)
#pragma unroll
                    for (int ni = 0; ni < 8; ni++)
                        acc[mi][ni] = __builtin_amdgcn_mfma_f32_16x16x32_bf16(
                            af[mi], bfr[ni], acc[mi][ni], 0, 0, 0);
            }
            __syncthreads();
        }

#pragma unroll
        for (int mi = 0; mi < 4; mi++) {
#pragma unroll
            for (int r4 = 0; r4 < 4; r4++) {
                const int row = moff + mi * 16 + lq * 4 + r4;
                if (m0 + row < ce) {
                    const int tok = tokrow[row];
                    const float tp = topp[tok];
#pragma unroll
                    for (int ni = 0; ni < 8; ni++) {
                        const size_t idx = (size_t)tok * DIM + n0 + noff + ni * 16 + lr;
                        out[idx] = hs[idx] + tp * acc[mi][ni][r4];
                    }
                }
            }
        }
    }
}

// ---------------------------------------------------------------------------
extern "C" void kernel_launch(void* const* d_in, const int* in_sizes, int n_in,
                              void* d_out, int out_size, void* d_ws, size_t ws_size,
                              hipStream_t stream)
{
    const float* hs  = (const float*)d_in[0];
    const float* lnw = (const float*)d_in[1];
    const float* rw  = (const float*)d_in[2];
    const float* wi  = (const float*)d_in[3];
    const float* wo  = (const float*)d_in[4];

    float* out        = (float*)d_out;
    float* out_logits = out + (size_t)N_TOK * DIM;
    float* out_eidx   = out_logits + (size_t)N_TOK * NEXP;

    char* ws = (char*)d_ws;
    size_t off = 0;
    int*   cnt     = (int*)(ws + off);         off += 256;
    int*   list    = (int*)(ws + off);         off += (size_t)N_TOK * 4;
    float* topp    = (float*)(ws + off);       off += (size_t)N_TOK * 4;
    int*   eidx    = (int*)(ws + off);         off += (size_t)N_TOK * 4;
    int*   blkhist = (int*)(ws + off);         off += 4096;
    int*   base    = (int*)(ws + off);         off += 4096;
    unsigned short* xn  = (unsigned short*)(ws + off); off += (size_t)N_TOK * DIM * 2;
    unsigned short* Hb  = (unsigned short*)(ws + off); off += (size_t)N_TOK * FFD * 2;
    unsigned short* wob = (unsigned short*)(ws + off);

    // wi^T (bf16 [e][F][D]) lives in d_out's first 37.75 MB: dead before
    // GEMM2's epilogue writes `out`.
    unsigned short* wib = (unsigned short*)d_out;

    k_setup<<<13312, 256, 0, stream>>>(wi, wib, wo, wob, hs, lnw, rw,
                                       out_logits, out_eidx, topp, eidx, xn);
    k_hist<<<64, 256, 0, stream>>>(eidx, blkhist);
    k_prefix<<<1, 512, 0, stream>>>(blkhist, base, cnt);
    k_scatter<<<64, 256, 0, stream>>>(eidx, base, list);
    k_gemm1<<<1632, 256, 0, stream>>>(xn, wib, list, cnt, Hb);
    k_gemm2<<<408, 256, 0, stream>>>(Hb, wob, list, cnt, hs, topp, out);
}

// Round 12
// 275.942 us; speedup vs baseline: 1.2485x; 1.0992x over previous
//
#include <hip/hip_runtime.h>
#include <math.h>

#define N_TOK 16384
#define DIM   768
#define FFD   3072
#define NEXP  8
#define EPSV  1e-6f

typedef __attribute__((ext_vector_type(4))) float f32x4;
typedef __attribute__((ext_vector_type(4))) unsigned short u16x4;
typedef __attribute__((ext_vector_type(8))) unsigned short u16x8;
typedef __attribute__((ext_vector_type(8))) __bf16 bf16x8;

static __device__ __forceinline__ unsigned short f2bf(float f) {
    unsigned int u = __builtin_bit_cast(unsigned int, f);
    u += 0x7fffu + ((u >> 16) & 1u);   // round-to-nearest-even
    return (unsigned short)(u >> 16);
}
static __device__ __forceinline__ bf16x8 as_bf(u16x8 v) {
    return __builtin_bit_cast(bf16x8, v);
}
static __device__ __forceinline__ void gload16(const void* g, void* l) {
    __builtin_amdgcn_global_load_lds(
        (const __attribute__((address_space(1))) unsigned int*)g,
        (__attribute__((address_space(3))) unsigned int*)l, 16, 0, 0);
}

// ---------------------------------------------------------------------------
// Fused setup kernel: blocks [0,4608) convert wi, [4608,9216) convert wo,
// [9216,13312) run RMSNorm+router.
// Router rewritten for coalesced rw access: lane owns expert e=lane&7 and
// d-slice d=(lane>>3)+8q, so rw[d*8+e] = rw[q*64+lane] -> one 256B segment
// per load (was 64 cache lines per load with the old per-lane-d gather:
// lanes 128B apart -> ~25M L1 transactions, the real k_setup limiter;
// bank conflicts were halved in R11 with no speedup -> not the limiter).
// xv is staged in per-wave LDS (reuses the transpose tile buffer).
// ---------------------------------------------------------------------------
__global__ __launch_bounds__(256) void k_setup(
    const float* __restrict__ wi, unsigned short* __restrict__ wib,
    const float* __restrict__ wo, unsigned short* __restrict__ wob,
    const float* __restrict__ x, const float* __restrict__ lnw,
    const float* __restrict__ rw,
    float* __restrict__ out_logits, float* __restrict__ out_eidx,
    float* __restrict__ topp, int* __restrict__ eidx,
    unsigned short* __restrict__ xn)
{
    __shared__ float tile[64][65];                // 16.6 KB, reused by router
    const int t = threadIdx.x;
    const int b = blockIdx.x;

    if (b < 9216) {
        const float* in;
        unsigned short* outp;
        int R, C, bb;
        if (b < 4608) { in = wi; outp = wib; R = DIM; C = FFD; bb = b; }
        else          { in = wo; outp = wob; R = FFD; C = DIM; bb = b - 4608; }
        const int bc = C >> 6, br = R >> 6;
        const int e = bb / (bc * br);
        const int rem = bb - e * bc * br;
        const int rt = rem / bc, ct = rem - rt * bc;
        {
            const int r = t >> 2, c4 = (t & 3) << 4;
            const float* src = in + ((size_t)e * R + rt * 64 + r) * C + ct * 64 + c4;
#pragma unroll
            for (int q = 0; q < 4; q++) {
                float4 f = ((const float4*)src)[q];
                tile[r][c4 + q * 4 + 0] = f.x;
                tile[r][c4 + q * 4 + 1] = f.y;
                tile[r][c4 + q * 4 + 2] = f.z;
                tile[r][c4 + q * 4 + 3] = f.w;
            }
        }
        __syncthreads();
        {
            const int c = t >> 2, r4 = (t & 3) << 4;
            u16x8 o0, o1;
#pragma unroll
            for (int j = 0; j < 8; j++)  o0[j] = f2bf(tile[r4 + j][c]);
#pragma unroll
            for (int j = 0; j < 8; j++)  o1[j] = f2bf(tile[r4 + 8 + j][c]);
            unsigned short* dst = outp + ((size_t)e * C + ct * 64 + c) * R + rt * 64 + r4;
            *(u16x8*)dst       = o0;
            *(u16x8*)(dst + 8) = o1;
        }
        return;
    }

    // ---- RMSNorm + router: one wave per token ----
    const int wid = t >> 6, lane = t & 63;
    const int tok = (b - 9216) * 4 + wid;
    const size_t base = (size_t)tok * DIM;
    float* xvs = ((float*)tile) + wid * 768;      // per-wave 3 KB slice

    float4 v[3];
#pragma unroll
    for (int j = 0; j < 3; j++)
        v[j] = *(const float4*)(x + base + lane * 4 + j * 256);
    float ss = 0.f;
#pragma unroll
    for (int j = 0; j < 3; j++)
        ss += v[j].x * v[j].x + v[j].y * v[j].y + v[j].z * v[j].z + v[j].w * v[j].w;
#pragma unroll
    for (int s = 32; s > 0; s >>= 1) ss += __shfl_xor(ss, s);
    const float rstd = rsqrtf(ss * (1.0f / DIM) + EPSV);

#pragma unroll
    for (int j = 0; j < 3; j++) {
        float4 lw = *(const float4*)(lnw + lane * 4 + j * 256);
        float xv0 = v[j].x * rstd * lw.x, xv1 = v[j].y * rstd * lw.y;
        float xv2 = v[j].z * rstd * lw.z, xv3 = v[j].w * rstd * lw.w;
        u16x4 pk = { f2bf(xv0), f2bf(xv1), f2bf(xv2), f2bf(xv3) };
        *(u16x4*)(xn + base + lane * 4 + j * 256) = pk;
        float4 xq = { xv0, xv1, xv2, xv3 };
        *(float4*)&xvs[lane * 4 + j * 256] = xq;
    }
    __syncthreads();                               // xvs visible to all lanes

    // coalesced router matvec: lane owns e=lane&7, d=(lane>>3)+8q
    float rp = 0.f;
#pragma unroll 8
    for (int q = 0; q < 96; q++) {
        float xvv = xvs[(lane >> 3) + q * 8];      // LDS broadcast
        float rwv = rw[q * 64 + lane];             // 256B coalesced
        rp = fmaf(xvv, rwv, rp);
    }
    rp += __shfl_xor(rp, 8);
    rp += __shfl_xor(rp, 16);
    rp += __shfl_xor(rp, 32);                      // rp = logit[lane&7]
    if (lane < 8) out_logits[(size_t)tok * 8 + lane] = rp;

    float mx = rp; int am = lane & 7;
#pragma unroll
    for (int s = 1; s < 8; s <<= 1) {
        float o = __shfl_xor(mx, s);
        int  oa = __shfl_xor(am, s);
        if (o > mx || (o == mx && oa < am)) { mx = o; am = oa; }
    }
    float se = expf(rp - mx);
    se += __shfl_xor(se, 1);
    se += __shfl_xor(se, 2);
    se += __shfl_xor(se, 4);
    if (lane == 0) {
        topp[tok] = 1.0f / se;
        out_eidx[tok] = (float)am;
        eidx[tok] = am;
    }
}

// ---------------------------------------------------------------------------
__global__ __launch_bounds__(256) void k_hist(
    const int* __restrict__ eidx, int* __restrict__ blkhist)
{
    __shared__ int h[8];
    if (threadIdx.x < 8) h[threadIdx.x] = 0;
    __syncthreads();
    atomicAdd(&h[eidx[blockIdx.x * 256 + threadIdx.x]], 1);
    __syncthreads();
    if (threadIdx.x < 8) blkhist[blockIdx.x * 8 + threadIdx.x] = h[threadIdx.x];
}

// ---------------------------------------------------------------------------
__global__ __launch_bounds__(512) void k_prefix(
    const int* __restrict__ blkhist, int* __restrict__ base,
    int* __restrict__ cnt)
{
    __shared__ int h[64 * 8];
    __shared__ int tot[8];
    __shared__ int eb[8];
    const int t = threadIdx.x;
    h[t] = blkhist[t];
    __syncthreads();
    const int b = t >> 3, e = t & 7;
    int s = 0;
    for (int bb = 0; bb < b; bb++) s += h[bb * 8 + e];
    if (b == 63) tot[e] = s + h[63 * 8 + e];
    __syncthreads();
    if (t == 0) {
        int p = 0;
#pragma unroll
        for (int q = 0; q < 8; q++) { eb[q] = p; p += tot[q]; }
    }
    __syncthreads();
    base[t] = eb[e] + s;
    if (t < 8) cnt[t] = tot[t];
}

// ---------------------------------------------------------------------------
__global__ __launch_bounds__(256) void k_scatter(
    const int* __restrict__ eidx, const int* __restrict__ base,
    int* __restrict__ list)
{
    __shared__ int wcnt[4][8];
    __shared__ int bb[8];
    const int t = threadIdx.x, b = blockIdx.x;
    const int lane = t & 63, wid = t >> 6;
    if (t < 8) bb[t] = base[b * 8 + t];
    const int tok = b * 256 + t;
    const int e = eidx[tok];
    int wrank = 0;
#pragma unroll
    for (int q = 0; q < 8; q++) {
        unsigned long long m = __ballot(e == q);
        if (e == q) wrank = __popcll(m & ((1ull << lane) - 1ull));
        if (lane == 0) wcnt[wid][q] = __popcll(m);
    }
    __syncthreads();
    int wbase = 0;
#pragma unroll
    for (int w = 0; w < 4; w++)
        if (w < wid) wbase += wcnt[w][e];
    list[bb[e] + wbase + wrank] = tok;
}

// ---------------------------------------------------------------------------
// GEMM1: 128x256 tile, BK=64, single-buffer 2-barrier (proven), A gathered
// via token list, H written in dense (permuted) row order.
// ---------------------------------------------------------------------------
__global__ __launch_bounds__(256, 2) void k_gemm1(
    const unsigned short* __restrict__ A, const unsigned short* __restrict__ Bw,
    const int* __restrict__ list, const int* __restrict__ cnt,
    unsigned short* __restrict__ Hout)
{
    constexpr int K   = DIM;
    constexpr int N   = FFD;
    constexpr int TNT = N / 256;                  // 12
    __shared__ unsigned short Asm[128 * 64];      // 16 KB
    __shared__ unsigned short Bsm[256 * 64];      // 32 KB
    __shared__ int tokrow[128];
    __shared__ int spref[9];
    __shared__ int ebase[8];

    const int t = threadIdx.x, lane = t & 63, wid = t >> 6;
    if (t == 0) {
        int p = 0, qq = 0;
        spref[0] = 0;
#pragma unroll
        for (int e = 0; e < 8; e++) {
            ebase[e] = qq; qq += cnt[e];
            p += (cnt[e] + 127) >> 7;
            spref[e + 1] = p;
        }
    }
    __syncthreads();
    const int total = spref[8] * TNT;
    const int moff = (wid >> 1) * 64, noff = (wid & 1) * 128;
    const int lr = lane & 15, lq = lane >> 4;

    const int nwg = gridDim.x;
    const int xcd = blockIdx.x & 7, rr8 = blockIdx.x >> 3;
    const int qd = nwg >> 3, rm = nwg & 7;
    const int bid = (xcd < rm ? xcd * (qd + 1) : rm * (qd + 1) + (xcd - rm) * qd) + rr8;

    int arow[4], asub[4], brow[8], bsub[8];
#pragma unroll
    for (int i = 0; i < 4; i++) {
        int c = (wid * 4 + i) * 64 + lane;
        arow[i] = c >> 3;
        asub[i] = (c & 7) ^ (arow[i] & 7);
    }
#pragma unroll
    for (int i = 0; i < 8; i++) {
        int c = (wid * 8 + i) * 64 + lane;
        brow[i] = c >> 3;
        bsub[i] = (c & 7) ^ (brow[i] & 7);
    }

    for (int w = bid; w < total; w += gridDim.x) {
        const int gm = w / TNT, tn = w - gm * TNT;
        int e = 0;
        while (gm >= spref[e + 1]) e++;
        const int ce = cnt[e], eb = ebase[e];
        const int m0 = (gm - spref[e]) * 128, n0 = tn * 256;

        __syncthreads();
        if (t < 128)
            tokrow[t] = (m0 + t < ce) ? list[eb + m0 + t] : list[eb];
        __syncthreads();

        const unsigned short* aP[4];
        const unsigned short* bP[8];
#pragma unroll
        for (int i = 0; i < 4; i++)
            aP[i] = A + (size_t)tokrow[arow[i]] * K + asub[i] * 8;
#pragma unroll
        for (int i = 0; i < 8; i++)
            bP[i] = Bw + ((size_t)e * N + n0 + brow[i]) * K + bsub[i] * 8;

        f32x4 acc[4][8];
#pragma unroll
        for (int mi = 0; mi < 4; mi++)
#pragma unroll
            for (int ni = 0; ni < 8; ni++) acc[mi][ni] = (f32x4){0, 0, 0, 0};

        for (int k0 = 0; k0 < K; k0 += 64) {
#pragma unroll
            for (int i = 0; i < 4; i++)
                gload16(aP[i] + k0, Asm + (wid * 4 + i) * 512);
#pragma unroll
            for (int i = 0; i < 8; i++)
                gload16(bP[i] + k0, Bsm + (wid * 8 + i) * 512);
            __syncthreads();
#pragma unroll
            for (int kf = 0; kf < 2; kf++) {
                const int phys = ((kf * 4 + lq) ^ (lr & 7)) * 8;
                bf16x8 af[4], bfr[8];
#pragma unroll
                for (int mi = 0; mi < 4; mi++)
                    af[mi] = as_bf(*(const u16x8*)&Asm[(moff + mi * 16 + lr) * 64 + phys]);
#pragma unroll
                for (int ni = 0; ni < 8; ni++)
                    bfr[ni] = as_bf(*(const u16x8*)&Bsm[(noff + ni * 16 + lr) * 64 + phys]);
#pragma unroll
                for (int mi = 0; mi < 4; mi++)
#pragma unroll
                    for (int ni = 0; ni < 8; ni++)
                        acc[mi][ni] = __builtin_amdgcn_mfma_f32_16x16x32_bf16(
                            af[mi], bfr[ni], acc[mi][ni], 0, 0, 0);
            }
            __syncthreads();
        }

#pragma unroll
        for (int mi = 0; mi < 4; mi++) {
#pragma unroll
            for (int r4 = 0; r4 < 4; r4++) {
                const int row = moff + mi * 16 + lq * 4 + r4;
                if (m0 + row < ce) {
                    unsigned short* hp = Hout + (size_t)(eb + m0 + row) * FFD + n0 + noff;
#pragma unroll
                    for (int ni = 0; ni < 8; ni++) {
                        float v = acc[mi][ni][r4];
                        v = v > 0.f ? v : 0.f;
                        hp[ni * 16 + lr] = f2bf(v);
                    }
                }
            }
        }
    }
}

// ---------------------------------------------------------------------------
// GEMM2: 128x256 tile, BK=64, single-buffer 2-barrier (proven), dense A rows
// from permuted H.  out[tok,:] = hs[tok,:] + topp[tok]*(Hperm @ WoT)
// ---------------------------------------------------------------------------
__global__ __launch_bounds__(256, 2) void k_gemm2(
    const unsigned short* __restrict__ A, const unsigned short* __restrict__ Bw,
    const int* __restrict__ list, const int* __restrict__ cnt,
    const float* __restrict__ hs, const float* __restrict__ topp,
    float* __restrict__ out)
{
    constexpr int K   = FFD;
    constexpr int N   = DIM;
    constexpr int TNT = N / 256;                  // 3
    __shared__ unsigned short Asm[128 * 64];      // 16 KB
    __shared__ unsigned short Bsm[256 * 64];      // 32 KB
    __shared__ int tokrow[128];
    __shared__ int spref[9];
    __shared__ int ebase[8];

    const int t = threadIdx.x, lane = t & 63, wid = t >> 6;
    if (t == 0) {
        int p = 0, qq = 0;
        spref[0] = 0;
#pragma unroll
        for (int e = 0; e < 8; e++) {
            ebase[e] = qq; qq += cnt[e];
            p += (cnt[e] + 127) >> 7;
            spref[e + 1] = p;
        }
    }
    __syncthreads();
    const int total = spref[8] * TNT;
    const int moff = (wid >> 1) * 64, noff = (wid & 1) * 128;
    const int lr = lane & 15, lq = lane >> 4;

    const int nwg = gridDim.x;
    const int xcd = blockIdx.x & 7, rr8 = blockIdx.x >> 3;
    const int qd = nwg >> 3, rm = nwg & 7;
    const int bid = (xcd < rm ? xcd * (qd + 1) : rm * (qd + 1) + (xcd - rm) * qd) + rr8;

    int arow[4], asub[4], brow[8], bsub[8];
#pragma unroll
    for (int i = 0; i < 4; i++) {
        int c = (wid * 4 + i) * 64 + lane;
        arow[i] = c >> 3;
        asub[i] = (c & 7) ^ (arow[i] & 7);
    }
#pragma unroll
    for (int i = 0; i < 8; i++) {
        int c = (wid * 8 + i) * 64 + lane;
        brow[i] = c >> 3;
        bsub[i] = (c & 7) ^ (brow[i] & 7);
    }

    for (int w = bid; w < total; w += gridDim.x) {
        const int gm = w / TNT, tn = w - gm * TNT;
        int e = 0;
        while (gm >= spref[e + 1]) e++;
        const int ce = cnt[e], eb = ebase[e];
        const int m0 = (gm - spref[e]) * 128, n0 = tn * 256;

        __syncthreads();
        if (t < 128)
            tokrow[t] = (m0 + t < ce) ? list[eb + m0 + t] : list[eb];
        __syncthreads();

        const unsigned short* aP[4];
        const unsigned short* bP[8];
#pragma unroll
        for (int i = 0; i < 4; i++) {
            const int drow = (m0 + arow[i] < ce) ? (m0 + arow[i]) : (ce - 1);
            aP[i] = A + (size_t)(eb + drow) * K + asub[i] * 8;
        }
#pragma unroll
        for (int i = 0; i < 8; i++)
            bP[i] = Bw + ((size_t)e * N + n0 + brow[i]) * K + bsub[i] * 8;

        f32x4 acc[4][8];
#pragma unroll
        for (int mi = 0; mi < 4; mi++)
#pragma unroll
            for (int ni = 0; ni < 8; ni++) acc[mi][ni] = (f32x4){0, 0, 0, 0};

        for (int k0 = 0; k0 < K; k0 += 64) {
#pragma unroll
            for (int i = 0; i < 4; i++)
                gload16(aP[i] + k0, Asm + (wid * 4 + i) * 512);
#pragma unroll
            for (int i = 0; i < 8; i++)
                gload16(bP[i] + k0, Bsm + (wid * 8 + i) * 512);
            __syncthreads();
#pragma unroll
            for (int kf = 0; kf < 2; kf++) {
                const int phys = ((kf * 4 + lq) ^ (lr & 7)) * 8;
                bf16x8 af[4], bfr[8];
#pragma unroll
                for (int mi = 0; mi < 4; mi++)
                    af[mi] = as_bf(*(const u16x8*)&Asm[(moff + mi * 16 + lr) * 64 + phys]);
#pragma unroll
                for (int ni = 0; ni < 8; ni++)
                    bfr[ni] = as_bf(*(const u16x8*)&Bsm[(noff + ni * 16 + lr) * 64 + phys]);
#pragma unroll
                for (int mi = 0; mi < 4; mi++)
#pragma unroll
                    for (int ni = 0; ni < 8; ni++)
                        acc[mi][ni] = __builtin_amdgcn_mfma_f32_16x16x32_bf16(
                            af[mi], bfr[ni], acc[mi][ni], 0, 0, 0);
            }
            __syncthreads();
        }

#pragma unroll
        for (int mi = 0; mi < 4; mi++) {
#pragma unroll
            for (int r4 = 0; r4 < 4; r4++) {
                const int row = moff + mi * 16 + lq * 4 + r4;
                if (m0 + row < ce) {
                    const int tok = tokrow[row];
                    const float tp = topp[tok];
#pragma unroll
                    for (int ni = 0; ni < 8; ni++) {
                        const size_t idx = (size_t)tok * DIM + n0 + noff + ni * 16 + lr;
                        out[idx] = hs[idx] + tp * acc[mi][ni][r4];
                    }
                }
            }
        }
    }
}

// ---------------------------------------------------------------------------
extern "C" void kernel_launch(void* const* d_in, const int* in_sizes, int n_in,
                              void* d_out, int out_size, void* d_ws, size_t ws_size,
                              hipStream_t stream)
{
    const float* hs  = (const float*)d_in[0];
    const float* lnw = (const float*)d_in[1];
    const float* rw  = (const float*)d_in[2];
    const float* wi  = (const float*)d_in[3];
    const float* wo  = (const float*)d_in[4];

    float* out        = (float*)d_out;
    float* out_logits = out + (size_t)N_TOK * DIM;
    float* out_eidx   = out_logits + (size_t)N_TOK * NEXP;

    char* ws = (char*)d_ws;
    size_t off = 0;
    int*   cnt     = (int*)(ws + off);         off += 256;
    int*   list    = (int*)(ws + off);         off += (size_t)N_TOK * 4;
    float* topp    = (float*)(ws + off);       off += (size_t)N_TOK * 4;
    int*   eidx    = (int*)(ws + off);         off += (size_t)N_TOK * 4;
    int*   blkhist = (int*)(ws + off);         off += 4096;
    int*   base    = (int*)(ws + off);         off += 4096;
    unsigned short* xn  = (unsigned short*)(ws + off); off += (size_t)N_TOK * DIM * 2;
    unsigned short* Hb  = (unsigned short*)(ws + off); off += (size_t)N_TOK * FFD * 2;
    unsigned short* wob = (unsigned short*)(ws + off);

    // wi^T (bf16 [e][F][D]) lives in d_out's first 37.75 MB: dead before
    // GEMM2's epilogue writes `out`.
    unsigned short* wib = (unsigned short*)d_out;

    k_setup<<<13312, 256, 0, stream>>>(wi, wib, wo, wob, hs, lnw, rw,
                                       out_logits, out_eidx, topp, eidx, xn);
    k_hist<<<64, 256, 0, stream>>>(eidx, blkhist);
    k_prefix<<<1, 512, 0, stream>>>(blkhist, base, cnt);
    k_scatter<<<64, 256, 0, stream>>>(eidx, base, list);
    k_gemm1<<<1632, 256, 0, stream>>>(xn, wib, list, cnt, Hb);
    k_gemm2<<<408, 256, 0, stream>>>(Hb, wob, list, cnt, hs, topp, out);
}